// Round 1
// baseline (189.779 us; speedup 1.0000x reference)
//
#include <hip/hip_runtime.h>
#include <cstdint>

#define NQ 20
#define DIM (1u << NQ)
#define NLAYERS 4

// ---------- host-side GF(2) mask helpers ----------
// Gray map g(x) = x ^ (x>>1). After l CNOT-chain layers the accumulated
// index transform is g^l. Pairing mask for Ry on bit b at layer l:
//   m = g^l(e_b)  (apply x ^= x>>1, l times, to 1<<b)
// Branch selector: logical bit b of g^{-l}(j) = parity(j & R),
//   R_k = bit_b(g^{-l}(e_k)); ginv = suffix-parity (bit m = XOR of bits >= m).

static unsigned pair_mask(int l, int b) {
    unsigned m = 1u << b;
    for (int k = 0; k < l; ++k) m ^= m >> 1;
    return m;
}
static unsigned ginv_apply(unsigned x) {
    x ^= x >> 1; x ^= x >> 2; x ^= x >> 4; x ^= x >> 8; x ^= x >> 16;
    return x;
}
static unsigned sel_mask(int l, int b) {
    unsigned R = 0;
    for (int k = 0; k < NQ; ++k) {
        unsigned w = 1u << k;
        for (int t = 0; t < l; ++t) w = ginv_apply(w);
        if ((w >> b) & 1u) R |= 1u << k;
    }
    return R;
}

struct GatesA { unsigned m[13]; unsigned R[13]; int layer; };
struct GatesB { unsigned m[7];  unsigned R[7];  int layer; };

// ---------- kernels ----------

__global__ __launch_bounds__(256) void k_init(const float* __restrict__ re,
                                              const float* __restrict__ im,
                                              float2* __restrict__ st) {
    unsigned i = blockIdx.x * 256u + threadIdx.x;
    st[i] = make_float2(re[i], im[i]);
}

// Gates on bits 0..12 (qubits 7..19). Contiguous 8192-amp tiles.
__global__ __launch_bounds__(256) void k_low(float2* __restrict__ st,
                                             const float* __restrict__ theta,
                                             GatesA gp) {
    __shared__ __align__(16) float2 lds[8192];
    const unsigned tid = threadIdx.x;
    const unsigned base = blockIdx.x << 13;

    float4* l4 = reinterpret_cast<float4*>(lds);
    const float4* g4 = reinterpret_cast<const float4*>(st + base);
#pragma unroll
    for (int k = 0; k < 16; ++k) l4[tid + (k << 8)] = g4[tid + (k << 8)];
    __syncthreads();

    for (int g = 0; g < 13; ++g) {
        const unsigned m = gp.m[g];
        const unsigned R = gp.R[g];
        const unsigned p = (unsigned)g;  // pivot = b = g (highest bit of m)
        // wave-uniform trig (b = g  ->  qubit q = 19-g)
        const float th = 0.5f * theta[gp.layer * NQ + (19 - g)];
        const float c = cosf(th), s = sinf(th);
#pragma unroll
        for (int k = 0; k < 16; ++k) {
            unsigned u  = tid + (unsigned)(k << 8);          // 4096 pairs
            unsigned t0 = ((u >> p) << (p + 1)) | (u & ((1u << p) - 1u));
            unsigned sel = __popc((base | t0) & R) & 1u;
            unsigned i0 = sel ? (t0 ^ m) : t0;               // logical-0 branch
            unsigned i1 = i0 ^ m;
            float2 v0 = lds[i0], v1 = lds[i1];
            lds[i0] = make_float2(c * v0.x - s * v1.x, c * v0.y - s * v1.y);
            lds[i1] = make_float2(s * v0.x + c * v1.x, s * v0.y + c * v1.y);
        }
        __syncthreads();
    }

    float4* gw = reinterpret_cast<float4*>(st + base);
#pragma unroll
    for (int k = 0; k < 16; ++k) gw[tid + (k << 8)] = l4[tid + (k << 8)];
}

// Gates on bits 13..19 (qubits 0..6); masks stay within bits 10..19.
// Tile: all 1024 combos of bits 19..10  x  8 contiguous elems (bits 2..0),
// fixed bits 9..3 = blockIdx.x. Local index t = (h<<3)|lo.
__global__ __launch_bounds__(256) void k_high(float2* __restrict__ st,
                                              const float* __restrict__ theta,
                                              GatesB gp) {
    __shared__ __align__(16) float2 lds[8192];
    const unsigned tid = threadIdx.x;
    const unsigned mid = blockIdx.x;  // bits 3..9 of the global index

    float4* l4 = reinterpret_cast<float4*>(lds);
    const float4* gsrc = reinterpret_cast<const float4*>(st);
#pragma unroll
    for (int k = 0; k < 16; ++k) {
        unsigned u = tid + (unsigned)(k << 8);   // float4 units: row h = u>>2
        unsigned h = u >> 2, q = u & 3u;
        l4[u] = gsrc[(h << 9) | (mid << 2) | q];
    }
    __syncthreads();

    for (int g = 0; g < 7; ++g) {
        const unsigned ml = gp.m[g] >> 7;        // global bit B -> local bit B-7
        const unsigned R  = gp.R[g];
        const unsigned pl = (unsigned)(6 + g);   // local pivot = b-7, b = 13+g
        const float th = 0.5f * theta[gp.layer * NQ + (6 - g)];  // q = 19-b
        const float c = cosf(th), s = sinf(th);
#pragma unroll
        for (int k = 0; k < 16; ++k) {
            unsigned u  = tid + (unsigned)(k << 8);
            unsigned t0 = ((u >> pl) << (pl + 1)) | (u & ((1u << pl) - 1u));
            unsigned j0 = ((t0 >> 3) << 10) | (mid << 3) | (t0 & 7u); // global idx
            unsigned sel = __popc(j0 & R) & 1u;
            unsigned i0 = sel ? (t0 ^ ml) : t0;
            unsigned i1 = i0 ^ ml;
            float2 v0 = lds[i0], v1 = lds[i1];
            lds[i0] = make_float2(c * v0.x - s * v1.x, c * v0.y - s * v1.y);
            lds[i1] = make_float2(s * v0.x + c * v1.x, s * v0.y + c * v1.y);
        }
        __syncthreads();
    }

    float4* gw = reinterpret_cast<float4*>(st);
#pragma unroll
    for (int k = 0; k < 16; ++k) {
        unsigned u = tid + (unsigned)(k << 8);
        unsigned h = u >> 2, q = u & 3u;
        gw[(h << 9) | (mid << 2) | q] = l4[u];
    }
}

// out_logical[i] = buf[g^4(i)] = buf[i ^ (i>>4)]; planar re/im output.
__global__ __launch_bounds__(256) void k_final(const float2* __restrict__ st,
                                               float* __restrict__ out) {
    unsigned i = blockIdx.x * 256u + threadIdx.x;
    float2 v = st[i ^ (i >> 4)];
    out[i] = v.x;
    out[DIM + i] = v.y;
}

// ---------- launch ----------

extern "C" void kernel_launch(void* const* d_in, const int* in_sizes, int n_in,
                              void* d_out, int out_size, void* d_ws, size_t ws_size,
                              hipStream_t stream) {
    const float* theta = (const float*)d_in[0];   // (4,20) float32
    const float* qr    = (const float*)d_in[1];   // (DIM,) float32
    const float* qi    = (const float*)d_in[2];   // (DIM,) float32
    float* out = (float*)d_out;                   // (2,DIM) float32
    float2* st = (float2*)d_ws;                   // DIM float2 = 8 MiB state

    k_init<<<DIM / 256, 256, 0, stream>>>(qr, qi, st);

    for (int l = 0; l < NLAYERS; ++l) {
        GatesA ga; ga.layer = l;
        for (int b = 0; b < 13; ++b) {
            ga.m[b] = pair_mask(l, b);
            ga.R[b] = sel_mask(l, b);
        }
        k_low<<<128, 256, 0, stream>>>(st, theta, ga);

        GatesB gb; gb.layer = l;
        for (int g = 0; g < 7; ++g) {
            gb.m[g] = pair_mask(l, 13 + g);
            gb.R[g] = sel_mask(l, 13 + g);
        }
        k_high<<<128, 256, 0, stream>>>(st, theta, gb);
    }

    k_final<<<DIM / 256, 256, 0, stream>>>(st, out);
}

// Round 2
// 117.223 us; speedup vs baseline: 1.6190x; 1.6190x over previous
//
#include <hip/hip_runtime.h>
#include <cstdint>

#define NQ 20
#define DIM (1u << NQ)

// ---------- host-side GF(2) mask helpers ----------
// Gray map g(x) = x ^ (x>>1) accumulates per CNOT-chain layer; gate (l,b)
// becomes a butterfly with pairing mask m = g^l(e_b) (spans [b-l, b]) and
// logical-branch selector parity(j & R), R = row b of g^{-l}.
static unsigned pair_mask(int l, int b) {
    unsigned m = 1u << b;
    for (int k = 0; k < l; ++k) m ^= m >> 1;
    return m;
}
static unsigned ginv_apply(unsigned x) {
    x ^= x >> 1; x ^= x >> 2; x ^= x >> 4; x ^= x >> 8; x ^= x >> 16;
    return x & 0xFFFFFu;
}
static unsigned sel_mask(int l, int b) {
    unsigned R = 0;
    for (int k = 0; k < NQ; ++k) {
        unsigned w = 1u << k;
        for (int t = 0; t < l; ++t) w = ginv_apply(w);
        if ((w >> b) & 1u) R |= 1u << k;
    }
    return R;
}

struct GateList {
    unsigned m[24];
    unsigned R[24];
    unsigned tix[24];   // trig index = l*20 + b
    int n;
};

// ---------- kernels ----------

// trig[l*20+b] = (cos, sin) of theta[l][19-b]/2 — hoists transcendentals.
__global__ __launch_bounds__(128) void k_trig(const float* __restrict__ theta,
                                              float2* __restrict__ trig) {
    int i = threadIdx.x;
    if (i < 80) {
        int l = i / NQ, b = i % NQ;
        float th = 0.5f * theta[l * NQ + (NQ - 1 - b)];
        trig[i] = make_float2(cosf(th), sinf(th));
    }
}

// Low window: gate masks within bits 0..12; contiguous 8192-amp tiles.
template<bool INIT>
__global__ __launch_bounds__(1024) void k_low(float2* __restrict__ st,
                                              const float* __restrict__ qr,
                                              const float* __restrict__ qi,
                                              const float2* __restrict__ trig,
                                              GateList gl) {
    __shared__ __align__(16) float2 lds[8192];
    const unsigned tid = threadIdx.x;
    const unsigned base = blockIdx.x << 13;

    if (INIT) {
        const float4* r4 = reinterpret_cast<const float4*>(qr) + (base >> 2);
        const float4* i4 = reinterpret_cast<const float4*>(qi) + (base >> 2);
#pragma unroll
        for (int k = 0; k < 2; ++k) {
            unsigned u = tid + (unsigned)(k << 10);
            float4 r = r4[u], im = i4[u];
            unsigned t = u << 2;
            lds[t + 0] = make_float2(r.x, im.x);
            lds[t + 1] = make_float2(r.y, im.y);
            lds[t + 2] = make_float2(r.z, im.z);
            lds[t + 3] = make_float2(r.w, im.w);
        }
    } else {
        float4* l4 = reinterpret_cast<float4*>(lds);
        const float4* g4 = reinterpret_cast<const float4*>(st + base);
#pragma unroll
        for (int k = 0; k < 4; ++k) l4[tid + (unsigned)(k << 10)] = g4[tid + (unsigned)(k << 10)];
    }
    __syncthreads();

    for (int g = 0; g < gl.n; ++g) {
        const unsigned m = gl.m[g];
        const unsigned R = gl.R[g];
        const unsigned p = 31u - (unsigned)__clz((int)m);   // pivot = top bit = b
        const float2 cs = trig[gl.tix[g]];
        const float c = cs.x, s = cs.y;
        const unsigned selb = (unsigned)__popc(base & R) & 1u;

        float2 va[4], vb[4];
        float ss[4];
        unsigned ta[4];
#pragma unroll
        for (int k = 0; k < 4; ++k) {
            unsigned u = tid + (unsigned)(k << 10);
            unsigned t0 = ((u >> p) << (p + 1)) | (u & ((1u << p) - 1u));
            unsigned sel = ((unsigned)__popc(t0 & R) + selb) & 1u;
            ta[k] = t0;
            ss[k] = sel ? s : -s;
            va[k] = lds[t0];
            vb[k] = lds[t0 ^ m];
        }
#pragma unroll
        for (int k = 0; k < 4; ++k) {
            float2 a = va[k], b = vb[k];
            float sk = ss[k];
            lds[ta[k]]     = make_float2(c * a.x + sk * b.x, c * a.y + sk * b.y);
            lds[ta[k] ^ m] = make_float2(c * b.x - sk * a.x, c * b.y - sk * a.y);
        }
        __syncthreads();
    }

    float4* l4 = reinterpret_cast<float4*>(lds);
    float4* g4 = reinterpret_cast<float4*>(st + base);
#pragma unroll
    for (int k = 0; k < 4; ++k) g4[tid + (unsigned)(k << 10)] = l4[tid + (unsigned)(k << 10)];
}

// High window: gate masks within bits 10..19. Tile = 1024 combos of bits
// 19..10 x 8 contiguous (bits 2..0); bits 9..3 = blockIdx. t = (h<<3)|lo.
__global__ __launch_bounds__(1024) void k_high(float2* __restrict__ st,
                                               const float2* __restrict__ trig,
                                               GateList gl) {
    __shared__ __align__(16) float2 lds[8192];
    const unsigned tid = threadIdx.x;
    const unsigned mid = blockIdx.x;

    float4* l4 = reinterpret_cast<float4*>(lds);
    const float4* gs = reinterpret_cast<const float4*>(st);
#pragma unroll
    for (int k = 0; k < 4; ++k) {
        unsigned u = tid + (unsigned)(k << 10);
        unsigned h = u >> 2, q = u & 3u;
        l4[u] = gs[(h << 9) | (mid << 2) | q];
    }
    __syncthreads();

    const unsigned mid3 = mid << 3;
    for (int g = 0; g < gl.n; ++g) {
        const unsigned mg = gl.m[g];
        const unsigned ml = mg >> 7;                         // global bit k -> local k-7
        const unsigned R = gl.R[g];
        const unsigned pl = (31u - (unsigned)__clz((int)mg)) - 7u;
        const float2 cs = trig[gl.tix[g]];
        const float c = cs.x, s = cs.y;
        const unsigned selb = (unsigned)__popc(mid3 & R) & 1u;

        float2 va[4], vb[4];
        float ss[4];
        unsigned ta[4];
#pragma unroll
        for (int k = 0; k < 4; ++k) {
            unsigned u = tid + (unsigned)(k << 10);
            unsigned t0 = ((u >> pl) << (pl + 1)) | (u & ((1u << pl) - 1u));
            unsigned jv = ((t0 >> 3) << 10) | (t0 & 7u);
            unsigned sel = ((unsigned)__popc(jv & R) + selb) & 1u;
            ta[k] = t0;
            ss[k] = sel ? s : -s;
            va[k] = lds[t0];
            vb[k] = lds[t0 ^ ml];
        }
#pragma unroll
        for (int k = 0; k < 4; ++k) {
            float2 a = va[k], b = vb[k];
            float sk = ss[k];
            lds[ta[k]]      = make_float2(c * a.x + sk * b.x, c * a.y + sk * b.y);
            lds[ta[k] ^ ml] = make_float2(c * b.x - sk * a.x, c * b.y - sk * a.y);
        }
        __syncthreads();
    }

#pragma unroll
    for (int k = 0; k < 4; ++k) {
        unsigned u = tid + (unsigned)(k << 10);
        unsigned h = u >> 2, q = u & 3u;
        reinterpret_cast<float4*>(st)[(h << 9) | (mid << 2) | q] = l4[u];
    }
}

// out_logical[i] = buf[g^4(i)] = buf[i ^ (i>>4)]; planar re/im output.
__global__ __launch_bounds__(256) void k_final(const float2* __restrict__ st,
                                               float* __restrict__ out) {
    unsigned i = blockIdx.x * 256u + threadIdx.x;
    float2 v = st[i ^ (i >> 4)];
    out[i] = v.x;
    out[DIM + i] = v.y;
}

// ---------- launch ----------

extern "C" void kernel_launch(void* const* d_in, const int* in_sizes, int n_in,
                              void* d_out, int out_size, void* d_ws, size_t ws_size,
                              hipStream_t stream) {
    const float* theta = (const float*)d_in[0];   // (4,20) float32
    const float* qr    = (const float*)d_in[1];
    const float* qi    = (const float*)d_in[2];
    float* out = (float*)d_out;
    float2* st = (float2*)d_ws;                                   // 8 MiB state
    float2* trig = (float2*)((char*)d_ws + (size_t)(8u << 20));   // 80 float2

    k_trig<<<1, 128, 0, stream>>>(theta, trig);

    auto add = [](GateList& gl, int l, int b) {
        gl.m[gl.n] = pair_mask(l, b);
        gl.R[gl.n] = sel_mask(l, b);
        gl.tix[gl.n] = (unsigned)(l * NQ + b);
        gl.n++;
    };

    // Ry gates commute within a layer -> reorder across low/high windows.
    GateList k1; k1.n = 0;                   // layer0 b=0..12
    for (int b = 0; b <= 12; ++b) add(k1, 0, b);
    k_low<true><<<128, 1024, 0, stream>>>(st, qr, qi, trig, k1);

    GateList k2; k2.n = 0;                   // layer0 b=13..19, layer1 b=11..19
    for (int b = 13; b <= 19; ++b) add(k2, 0, b);
    for (int b = 11; b <= 19; ++b) add(k2, 1, b);
    k_high<<<128, 1024, 0, stream>>>(st, trig, k2);

    GateList k3; k3.n = 0;                   // layer1 b=0..10, layer2 b=0..12
    for (int b = 0; b <= 10; ++b) add(k3, 1, b);
    for (int b = 0; b <= 12; ++b) add(k3, 2, b);
    k_low<false><<<128, 1024, 0, stream>>>(st, qr, qi, trig, k3);

    GateList k4; k4.n = 0;                   // layer2 b=13..19, layer3 b=13..19
    for (int b = 13; b <= 19; ++b) add(k4, 2, b);
    for (int b = 13; b <= 19; ++b) add(k4, 3, b);
    k_high<<<128, 1024, 0, stream>>>(st, trig, k4);

    GateList k5; k5.n = 0;                   // layer3 b=0..12
    for (int b = 0; b <= 12; ++b) add(k5, 3, b);
    k_low<false><<<128, 1024, 0, stream>>>(st, qr, qi, trig, k5);

    k_final<<<DIM / 256, 256, 0, stream>>>(st, out);
}

// Round 3
// 67.375 us; speedup vs baseline: 2.8168x; 1.7399x over previous
//
#include <hip/hip_runtime.h>
#include <cstdint>

#define NQ 20
#define DIM (1u << NQ)

// ================= constexpr GF(2) machinery =================
// Gray map g(x)=x^(x>>1) accumulates per CNOT-chain layer. Gate (l,b) is a
// butterfly with mask m=g^l(e_b) (span [b-l,b]) and selector parity(j&R),
// R = row b of g^{-l}. Final output gather: logical[i] = buf[i ^ (i>>4)].
constexpr unsigned cpair_mask(int l, int b) {
    unsigned m = 1u << b;
    for (int k = 0; k < l; ++k) m ^= m >> 1;
    return m;
}
constexpr unsigned cginv1(unsigned x) {
    x ^= x >> 1; x ^= x >> 2; x ^= x >> 4; x ^= x >> 8; x ^= x >> 16;
    return x & 0xFFFFFu;
}
constexpr unsigned csel_mask(int l, int b) {
    unsigned R = 0;
    for (int k = 0; k < NQ; ++k) {
        unsigned w = 1u << k;
        for (int t = 0; t < l; ++t) w = cginv1(w);
        if ((w >> b) & 1u) R |= 1u << k;
    }
    return R;
}
constexpr int cpopc(unsigned x) { int c = 0; while (x) { c += x & 1; x >>= 1; } return c; }

struct GateC { unsigned R; unsigned sb; int l; int b; int valid; int tix; };
struct GroupC { int pv[3]; unsigned gxs[8]; GateC gt[3]; };
struct SchedC { GroupC g[8]; int ng; };
struct TrigL  { int l[24]; int b[24]; int n; };

constexpr void add_group(SchedC& s, int& tix,
                         int l0, int b0, int l1, int b1, int l2, int b2) {
    GroupC g{};
    int ls[3] = {l0, l1, l2}; int bs[3] = {b0, b1, b2};
    unsigned m[3] = {0, 0, 0};
    for (int j = 0; j < 3; ++j) {
        bool val = ls[j] >= 0;
        m[j] = val ? cpair_mask(ls[j], bs[j]) : (1u << bs[j]);   // dummy: plain bit
        g.gt[j].R = val ? csel_mask(ls[j], bs[j]) : 0u;
        g.gt[j].valid = val ? 1 : 0;
        g.gt[j].l = ls[j]; g.gt[j].b = bs[j];
        g.gt[j].tix = val ? tix++ : 0;
    }
    for (int e = 0; e < 8; ++e) {
        unsigned x = 0;
        for (int j = 0; j < 3; ++j) if ((e >> j) & 1) x ^= m[j];
        g.gxs[e] = x;
    }
    for (int j = 0; j < 3; ++j) {
        unsigned sb = 0;
        for (int e = 0; e < 8; ++e) if (cpopc(g.gxs[e] & g.gt[j].R) & 1) sb |= (1u << e);
        g.gt[j].sb = sb;
    }
    int pv[3] = {0, 0, 0};
    for (int j = 0; j < 3; ++j) { int p = 0; for (int k = 0; k < NQ; ++k) if ((m[j] >> k) & 1) p = k; pv[j] = p; }
    for (int a = 0; a < 2; ++a)
        for (int c = 0; c < 2 - a; ++c)
            if (pv[c] > pv[c + 1]) { int t = pv[c]; pv[c] = pv[c + 1]; pv[c + 1] = t; }
    g.pv[0] = pv[0]; g.pv[1] = pv[1]; g.pv[2] = pv[2];
    s.g[s.ng] = g; s.ng++;
}

constexpr SchedC mk_sched(int kid) {
    SchedC s{}; int tix = 0;
    if (kid == 0) {                                  // K1: l0 b0..11
        for (int b = 0; b < 12; b += 3) add_group(s, tix, 0, b, 0, b + 1, 0, b + 2);
    } else if (kid == 1) {                           // K2: l0 b12..19, l1 b12..19
        add_group(s, tix, 0, 12, 0, 13, 0, 14);
        add_group(s, tix, 0, 15, 0, 16, 0, 17);
        add_group(s, tix, 0, 18, 0, 19, 1, 12);
        add_group(s, tix, 1, 13, 1, 14, 1, 15);
        add_group(s, tix, 1, 16, 1, 17, 1, 18);
        add_group(s, tix, 1, 19, -1, 17, -1, 18);    // 2 identity pads
    } else if (kid == 2) {                           // K3: l1 b0..11, l2 b0..11
        for (int b = 0; b < 12; b += 3) add_group(s, tix, 1, b, 1, b + 1, 1, b + 2);
        for (int b = 0; b < 12; b += 3) add_group(s, tix, 2, b, 2, b + 1, 2, b + 2);
    } else if (kid == 3) {                           // K4: l2 b12..19, l3 b13..19
        add_group(s, tix, 2, 12, 2, 13, 2, 14);
        add_group(s, tix, 2, 15, 2, 16, 2, 17);
        add_group(s, tix, 2, 18, 2, 19, 3, 13);
        add_group(s, tix, 3, 14, 3, 15, 3, 16);
        add_group(s, tix, 3, 17, 3, 18, 3, 19);
    } else {                                         // K5: l3 b0..11
        for (int b = 0; b < 12; b += 3) add_group(s, tix, 3, b, 3, b + 1, 3, b + 2);
    }
    return s;
}
constexpr TrigL mk_trig(int kid) {
    SchedC s = mk_sched(kid); TrigL t{};
    for (int gi = 0; gi < s.ng; ++gi)
        for (int j = 0; j < 3; ++j)
            if (s.g[gi].gt[j].valid) { t.l[t.n] = s.g[gi].gt[j].l; t.b[t.n] = s.g[gi].gt[j].b; t.n++; }
    return t;
}

// LDS swizzle (involution): keeps all group ds_read/write at inherent 4-slot min.
__device__ __forceinline__ unsigned swz(unsigned t) { return t ^ ((t >> 5) & 0xFu); }
constexpr unsigned cswz(unsigned t) { return t ^ ((t >> 5) & 0xFu); }

template<int LO>
__device__ __forceinline__ unsigned gmap(unsigned t, unsigned mid) {
    if constexpr (LO == 12) return (mid << 12) | t;
    else return ((t >> LO) << (LO + 8)) | (mid << LO) | (t & ((1u << LO) - 1u));
}

// ================= gate kernel =================
// 4096-amp tile in LDS; 512 threads x 8-amp cosets; 3 gates per LDS round.
template<int KID, int LO, bool INIT>
__global__ __launch_bounds__(512) void k_gates(float2* __restrict__ st,
                                               const float* __restrict__ qr,
                                               const float* __restrict__ qi,
                                               const float* __restrict__ theta) {
    constexpr SchedC S = mk_sched(KID);
    constexpr TrigL  T = mk_trig(KID);
    constexpr int SHIFT = (LO == 12) ? 0 : 8;

    __shared__ __align__(16) float2 lds[4096 + 32];
    float2* trigS = lds + 4096;
    float4* lds4 = reinterpret_cast<float4*>(lds);
    const unsigned tid = threadIdx.x;
    const unsigned mid = blockIdx.x;

    // per-block trig table (uniform, tiny)
    if (tid < (unsigned)T.n) {
        float th = 0.5f * theta[T.l[tid] * NQ + (NQ - 1 - T.b[tid])];
        trigS[tid] = make_float2(cosf(th), sinf(th));
    }

    // ---- stage in ----
    if (INIT) {
        const float4* r4 = reinterpret_cast<const float4*>(qr);
        const float4* i4 = reinterpret_cast<const float4*>(qi);
#pragma unroll
        for (int k = 0; k < 2; ++k) {
            unsigned u4 = tid + (unsigned)(k << 9);          // float4-of-float = 4 amps
            float4 r = r4[(mid << 10) + u4], im = i4[(mid << 10) + u4];
            unsigned t = u4 << 2;
            unsigned sw = swz(t);
            unsigned b4 = sw & ~3u, lo2 = sw & 3u;
            lds[b4 | (0u ^ lo2)] = make_float2(r.x, im.x);
            lds[b4 | (1u ^ lo2)] = make_float2(r.y, im.y);
            lds[b4 | (2u ^ lo2)] = make_float2(r.z, im.z);
            lds[b4 | (3u ^ lo2)] = make_float2(r.w, im.w);
        }
    } else {
        const float4* s4 = reinterpret_cast<const float4*>(st);
#pragma unroll
        for (int k = 0; k < 4; ++k) {
            unsigned u4 = tid + (unsigned)(k << 9);          // float4-of-float2 = 2 amps
            unsigned t = u4 << 1;
            unsigned g = gmap<LO>(t, mid);
            float4 d = s4[g >> 1];
            unsigned sw = swz(t);
            float4 e = (sw & 1u) ? make_float4(d.z, d.w, d.x, d.y) : d;
            lds4[sw >> 1] = e;
        }
    }
    __syncthreads();

    // ---- gate groups ----
#pragma unroll
    for (int gi = 0; gi < S.ng; ++gi) {
        unsigned t0 = tid;
        {
            const unsigned p0 = (unsigned)(S.g[gi].pv[0] - SHIFT);
            t0 = ((t0 >> p0) << (p0 + 1)) | (t0 & ((1u << p0) - 1u));
            const unsigned p1 = (unsigned)(S.g[gi].pv[1] - SHIFT);
            t0 = ((t0 >> p1) << (p1 + 1)) | (t0 & ((1u << p1) - 1u));
            const unsigned p2 = (unsigned)(S.g[gi].pv[2] - SHIFT);
            t0 = ((t0 >> p2) << (p2 + 1)) | (t0 & ((1u << p2) - 1u));
        }
        const unsigned g0 = gmap<LO>(t0, mid);     // global index (for selector parity)
        const unsigned sz0 = swz(t0);

        float2 v[8]; unsigned ad[8];
#pragma unroll
        for (int e = 0; e < 8; ++e) {
            const unsigned lx = S.g[gi].gxs[e] >> SHIFT;
            ad[e] = sz0 ^ cswz(lx);                // cswz(lx) folds to an immediate
            v[e] = lds[ad[e]];
        }
#pragma unroll
        for (int j = 0; j < 3; ++j) {
            if (S.g[gi].gt[j].valid) {
                const float2 cs = trigS[S.g[gi].gt[j].tix];
                const float c = cs.x, s = cs.y;
                const unsigned par = (unsigned)__popc(g0 & S.g[gi].gt[j].R) & 1u;
                const float sp = par ? s : -s;     // sigma when sb-bit = 0
                const float sn = -sp;              // sigma when sb-bit = 1
#pragma unroll
                for (int pr = 0; pr < 4; ++pr) {
                    constexpr int BASE[3][4] = {{0, 2, 4, 6}, {0, 1, 4, 5}, {0, 1, 2, 3}};
                    const int ea = BASE[j][pr];
                    const int eb = ea | (1 << j);
                    const float sg = ((S.g[gi].gt[j].sb >> ea) & 1u) ? sn : sp;
                    const float2 a = v[ea], b = v[eb];
                    v[ea] = make_float2(c * a.x + sg * b.x, c * a.y + sg * b.y);
                    v[eb] = make_float2(c * b.x - sg * a.x, c * b.y - sg * a.y);
                }
            }
        }
#pragma unroll
        for (int e = 0; e < 8; ++e) lds[ad[e]] = v[e];
        __syncthreads();
    }

    // ---- stage out ----
    float4* s4o = reinterpret_cast<float4*>(st);
#pragma unroll
    for (int k = 0; k < 4; ++k) {
        unsigned u4 = tid + (unsigned)(k << 9);
        unsigned t = u4 << 1;
        unsigned g = gmap<LO>(t, mid);
        unsigned sw = swz(t);
        float4 e = lds4[sw >> 1];
        float4 d = (sw & 1u) ? make_float4(e.z, e.w, e.x, e.y) : e;
        s4o[g >> 1] = d;
    }
}

// ================= final: gate (3,12) + gather + planar split =================
__global__ __launch_bounds__(256) void k_final(const float2* __restrict__ st,
                                               const float* __restrict__ theta,
                                               float* __restrict__ out) {
    constexpr unsigned FM = cpair_mask(3, 12);     // 0x1E00 (bits 9..12, even)
    constexpr unsigned FR = csel_mask(3, 12);      // bits >= 12 only
    const unsigned i2 = blockIdx.x * 256u + threadIdx.x;   // elem pair (2*i2, 2*i2+1)
    const unsigned i = i2 << 1;
    const unsigned j = i ^ (i >> 4);
    const float th = 0.5f * theta[3 * NQ + (NQ - 1 - 12)];
    const float c = cosf(th), s = sinf(th);

    const float4* s4 = reinterpret_cast<const float4*>(st);
    float4 A = s4[j >> 1];
    float4 B = s4[(j ^ FM) >> 1];
    const unsigned par = (unsigned)__popc(j & FR) & 1u;    // same for both elems (FR bit0=0)
    const float sg = par ? s : -s;

    float2 a0, a1, b0, b1;
    if (j & 1u) { a0 = make_float2(A.z, A.w); a1 = make_float2(A.x, A.y);
                  b0 = make_float2(B.z, B.w); b1 = make_float2(B.x, B.y); }
    else        { a0 = make_float2(A.x, A.y); a1 = make_float2(A.z, A.w);
                  b0 = make_float2(B.x, B.y); b1 = make_float2(B.z, B.w); }

    const float2 o0 = make_float2(c * a0.x + sg * b0.x, c * a0.y + sg * b0.y);
    const float2 o1 = make_float2(c * a1.x + sg * b1.x, c * a1.y + sg * b1.y);
    reinterpret_cast<float2*>(out)[i2] = make_float2(o0.x, o1.x);
    reinterpret_cast<float2*>(out + DIM)[i2] = make_float2(o0.y, o1.y);
}

// ================= launch =================
extern "C" void kernel_launch(void* const* d_in, const int* in_sizes, int n_in,
                              void* d_out, int out_size, void* d_ws, size_t ws_size,
                              hipStream_t stream) {
    const float* theta = (const float*)d_in[0];   // (4,20) float32
    const float* qr    = (const float*)d_in[1];
    const float* qi    = (const float*)d_in[2];
    float* out = (float*)d_out;
    float2* st = (float2*)d_ws;                   // 8 MiB state

    k_gates<0, 12, true ><<<256, 512, 0, stream>>>(st, qr, qi, theta);
    k_gates<1,  3, false><<<256, 512, 0, stream>>>(st, qr, qi, theta);
    k_gates<2, 12, false><<<256, 512, 0, stream>>>(st, qr, qi, theta);
    k_gates<3,  2, false><<<256, 512, 0, stream>>>(st, qr, qi, theta);
    k_gates<4, 12, false><<<256, 512, 0, stream>>>(st, qr, qi, theta);
    k_final<<<DIM / 512, 256, 0, stream>>>(st, theta, out);
}